// Round 1
// baseline (676.887 us; speedup 1.0000x reference)
//
#include <hip/hip_runtime.h>
#include <hip/hip_bf16.h>

// Problem constants (match reference)
#define V_WORDS 32000
#define NSPEC 4
#define DIM 128
#define LATENT 10000
#define TOTAL_NGRAMS 704000
#define NTOK (8 * 1024)

typedef __attribute__((ext_vector_type(4))) float f32x4;
typedef __attribute__((ext_vector_type(8))) short short8;

__device__ __forceinline__ short f2bf(float f) {
    __hip_bfloat16 h = __float2bfloat16(f);
    return *reinterpret_cast<short*>(&h);
}

// ---------------------------------------------------------------------------
// Kernel 1: EmbeddingBag(sum) via sorted segment_ids + tanh
// one block (128 threads) per output word; binary search the segment bounds.
// ---------------------------------------------------------------------------
__global__ void seg_sum_tanh(const int* __restrict__ ngram_ids,
                             const int* __restrict__ seg_ids,
                             const float* __restrict__ W,   // [32001,128]
                             float* __restrict__ lang) {    // [32000,128]
    int v = blockIdx.x;
    int t = threadIdx.x;  // 0..127
    // lower_bound(v)
    int lo = 0, hi = TOTAL_NGRAMS;
    while (lo < hi) { int m = (lo + hi) >> 1; if (seg_ids[m] < v) lo = m + 1; else hi = m; }
    int start = lo;
    hi = TOTAL_NGRAMS;
    while (lo < hi) { int m = (lo + hi) >> 1; if (seg_ids[m] < v + 1) lo = m + 1; else hi = m; }
    int end = lo;
    float acc = 0.f;
    for (int j = start; j < end; ++j) {
        int id = ngram_ids[j];                 // uniform across block -> broadcast
        acc += W[(size_t)id * DIM + t];        // coalesced 512B row read
    }
    lang[(size_t)v * DIM + t] = tanhf(acc);
}

// ---------------------------------------------------------------------------
// Kernel 2: latent fp32 -> bf16 copy + bf16 transpose (for PV contiguous reads)
// block (32,8), 32x32 tiles via LDS.
// ---------------------------------------------------------------------------
__global__ void conv_latent(const float* __restrict__ latent,  // [10000][128]
                            short* __restrict__ latbf,         // [10000][128]
                            short* __restrict__ latTbf) {      // [128][10000]
    __shared__ float tile[32][33];
    int n0 = blockIdx.x * 32;
    int d0 = blockIdx.y * 32;
    int tx = threadIdx.x;   // 0..31
    int ty = threadIdx.y;   // 0..7
    for (int k = 0; k < 32; k += 8) {
        int n = n0 + ty + k;
        float val = (n < LATENT) ? latent[(size_t)n * DIM + d0 + tx] : 0.f;
        tile[ty + k][tx] = val;
        if (n < LATENT) latbf[(size_t)n * DIM + d0 + tx] = f2bf(val);
    }
    __syncthreads();
    for (int k = 0; k < 32; k += 8) {
        int d = d0 + ty + k;
        int n = n0 + tx;
        if (n < LATENT) latTbf[(size_t)d * LATENT + n] = f2bf(tile[tx][ty + k]);
    }
}

// ---------------------------------------------------------------------------
// Kernel 3: flash-style  token = lang + softmax(lang @ latent^T) @ latent
// 500 blocks x 256 threads (4 waves). BQ=64 (16 q-rows/wave), BK=64.
// scores are tiny (|S| < ~0.3) so online-max is skipped: P = exp(S).
// LDS tiles XOR-swizzled on 16B chunks: chunk ^= (row & 7)  (G4 fix for the
// 32-way bank conflict of row-major D=128 tiles).
// ---------------------------------------------------------------------------
#define BQ 64
#define BK 64

__global__ __launch_bounds__(256, 4)
void flash_latent(const float* lang,              // [V][128]  (read; same buf as token)
                  const short* __restrict__ latbf,   // [LATENT][128]
                  const short* __restrict__ latTbf,  // [128][LATENT]
                  float* token) {                 // [V][128]  (write)
    __shared__ short Klds[BK * DIM];     // [64][128] bf16, swizzled
    __shared__ short Vtlds[DIM * BK];    // [128][64] bf16, swizzled
    __shared__ short Plds[4 * 16 * BK];  // per-wave [16][64] bf16, swizzled

    const int tid = threadIdx.x;
    const int w   = tid >> 6;
    const int l   = tid & 63;
    const int l16 = l & 15;
    const int g   = l >> 4;

    const int qbase = blockIdx.x * BQ + w * 16;

    // Q fragments in registers: lane holds Q[l16][c*32 + g*8 + 0..7]
    short8 qf[4];
    {
        const float* qrow = lang + (size_t)(qbase + l16) * DIM;
        for (int c = 0; c < 4; ++c) {
            short8 vv;
            for (int j = 0; j < 8; ++j) vv[j] = f2bf(qrow[c * 32 + g * 8 + j]);
            qf[c] = vv;
        }
    }

    f32x4 o[8];
    for (int s = 0; s < 8; ++s) o[s] = (f32x4){0.f, 0.f, 0.f, 0.f};
    float lsum[4] = {0.f, 0.f, 0.f, 0.f};

    const int niter = (LATENT + BK - 1) / BK;  // 157 (tail = 16 valid k)
    for (int kt = 0; kt < niter; ++kt) {
        const int k0 = kt * BK;
        __syncthreads();  // all waves done reading previous tiles
        // stage K tile [64][128]: 1024 16B chunks, 4 per thread
        for (int i = 0; i < 4; ++i) {
            int c  = tid + i * 256;
            int r  = c >> 4, ck = c & 15;
            int gk = k0 + r; if (gk > LATENT - 1) gk = LATENT - 1;  // clamp; masked via P
            short8 vv = *reinterpret_cast<const short8*>(latbf + (size_t)gk * DIM + ck * 8);
            *reinterpret_cast<short8*>(&Klds[r * DIM + ((ck ^ (r & 7)) * 8)]) = vv;
        }
        // stage Vt tile [128][64]
        for (int i = 0; i < 4; ++i) {
            int c  = tid + i * 256;
            int d  = c >> 3, ck = c & 7;
            int gk = k0 + ck * 8;
            short8 vv;
            if (gk + 7 < LATENT)
                vv = *reinterpret_cast<const short8*>(latTbf + (size_t)d * LATENT + gk);
            else
                vv = (short8){0, 0, 0, 0, 0, 0, 0, 0};
            *reinterpret_cast<short8*>(&Vtlds[d * BK + ((ck ^ (d & 7)) * 8)]) = vv;
        }
        __syncthreads();

        // S = Q * Ktile^T  : D[q][k] tiles, 4 ktiles x 4 d-chunks
        f32x4 s[4];
        for (int t = 0; t < 4; ++t) s[t] = (f32x4){0.f, 0.f, 0.f, 0.f};
        for (int t = 0; t < 4; ++t) {
            int row = t * 16 + l16;
            for (int c = 0; c < 4; ++c) {
                short8 b = *reinterpret_cast<const short8*>(
                    &Klds[row * DIM + (((c * 4 + g) ^ (row & 7)) * 8)]);
                s[t] = __builtin_amdgcn_mfma_f32_16x16x32_bf16(qf[c], b, s[t], 0, 0, 0);
            }
        }

        // P = exp(S) (no max needed: |S| < ~0.3), accumulate row-sums, write P->LDS
        for (int t = 0; t < 4; ++t) {
            int kg = k0 + t * 16 + l16;
            bool valid = kg < LATENT;
            for (int j = 0; j < 4; ++j) {
                float p = valid ? __expf(s[t][j]) : 0.f;
                lsum[j] += p;
                int prow  = g * 4 + j;         // local q row 0..15
                int e     = t * 16 + l16;      // k elem 0..63
                int chunk = (e >> 3) ^ (prow & 7);
                Plds[w * 16 * BK + prow * BK + chunk * 8 + (e & 7)] = f2bf(p);
            }
        }
        // same-wave DS ops complete in order -> no barrier needed before P reads

        // O += P * Vtile
        short8 pa[2];
        for (int c2 = 0; c2 < 2; ++c2) {
            int prow  = l16;
            int chunk = (c2 * 4 + g) ^ (prow & 7);
            pa[c2] = *reinterpret_cast<const short8*>(&Plds[w * 16 * BK + prow * BK + chunk * 8]);
        }
        for (int sub = 0; sub < 8; ++sub) {
            int drow = sub * 16 + l16;
            for (int c2 = 0; c2 < 2; ++c2) {
                int chunk = (c2 * 4 + g) ^ (drow & 7);
                short8 b = *reinterpret_cast<const short8*>(&Vtlds[drow * BK + chunk * 8]);
                o[sub] = __builtin_amdgcn_mfma_f32_16x16x32_bf16(pa[c2], b, o[sub], 0, 0, 0);
            }
        }
    }

    // full row-sums: reduce across the 16 lanes holding each row's columns
    for (int j = 0; j < 4; ++j) {
        float vv = lsum[j];
        vv += __shfl_xor(vv, 1, 64);
        vv += __shfl_xor(vv, 2, 64);
        vv += __shfl_xor(vv, 4, 64);
        vv += __shfl_xor(vv, 8, 64);
        lsum[j] = vv;
    }

    // epilogue: token = lang + O / lsum   (in-place over lang; block owns its rows)
    for (int sub = 0; sub < 8; ++sub) {
        for (int j = 0; j < 4; ++j) {
            int grow = qbase + g * 4 + j;
            int col  = sub * 16 + l16;
            float val = lang[(size_t)grow * DIM + col] + o[sub][j] / lsum[j];
            token[(size_t)grow * DIM + col] = val;
        }
    }
}

// ---------------------------------------------------------------------------
// Kernel 4: final gather  out[i] = (x<4) ? special[x] : token[x-4]
// ---------------------------------------------------------------------------
__global__ void gather_out(const int* __restrict__ x,
                           const float* __restrict__ token,
                           const float* __restrict__ special,
                           float* __restrict__ out) {
    int i = blockIdx.x;   // 0..8191
    int t = threadIdx.x;  // 0..127
    int id = x[i];
    float v = (id < NSPEC) ? special[(size_t)id * DIM + t]
                           : token[(size_t)(id - NSPEC) * DIM + t];
    out[(size_t)i * DIM + t] = v;
}

// ---------------------------------------------------------------------------
extern "C" void kernel_launch(void* const* d_in, const int* in_sizes, int n_in,
                              void* d_out, int out_size, void* d_ws, size_t ws_size,
                              hipStream_t stream) {
    const int*   x        = (const int*)d_in[0];
    const int*   ngram_id = (const int*)d_in[1];
    const int*   seg_id   = (const int*)d_in[2];
    const float* W        = (const float*)d_in[3];   // [32001,128]
    const float* latent   = (const float*)d_in[4];   // [10000,128]
    const float* special  = (const float*)d_in[5];   // [4,128]
    float* out = (float*)d_out;

    // workspace layout (21,504,000 B total)
    char* ws = (char*)d_ws;
    float* lang   = (float*)ws;                        // [32000][128] f32 (becomes token_emb)
    short* latbf  = (short*)(ws + 16384000);           // [10000][128] bf16
    short* latTbf = (short*)(ws + 18944000);           // [128][10000] bf16

    seg_sum_tanh<<<V_WORDS, 128, 0, stream>>>(ngram_id, seg_id, W, lang);
    conv_latent<<<dim3((LATENT + 31) / 32, DIM / 32), dim3(32, 8), 0, stream>>>(latent, latbf, latTbf);
    flash_latent<<<V_WORDS / BQ, 256, 0, stream>>>(lang, latbf, latTbf, lang);
    gather_out<<<NTOK, 128, 0, stream>>>(x, lang, special, out);
}

// Round 2
// 177.417 us; speedup vs baseline: 3.8152x; 3.8152x over previous
//
#include <hip/hip_runtime.h>
#include <hip/hip_bf16.h>

// Problem constants
#define V_WORDS 32000
#define NSPEC 4
#define DIM 128
#define LATENT 10000
#define LT_STRIDE 10112      // padded col count for latTbf rows (mult of 64, 16B-aligned)
#define TOTAL_NGRAMS 704000
#define NTOK 8192
#define MAXU 8192            // worst-case unique non-special ids
#define KSPLIT 8
#define KCH 1280             // k-range per split (last split: 10000-7*1280=1040)
#define BK 64

typedef __attribute__((ext_vector_type(4))) float f32x4;
typedef __attribute__((ext_vector_type(8))) short short8;

__device__ __forceinline__ short f2bf(float f) {
    __hip_bfloat16 h = __float2bfloat16(f);
    return *reinterpret_cast<short*>(&h);
}
__device__ __forceinline__ float bf2f(short s) {
    unsigned u = ((unsigned)(unsigned short)s) << 16;
    return __uint_as_float(u);
}

// async global->LDS 16B (linear LDS dest = uniform base + lane*16)
__device__ __forceinline__ void gl_lds16(const short* src, short* dst) {
    __builtin_amdgcn_global_load_lds(
        (const __attribute__((address_space(1))) void*)src,
        (__attribute__((address_space(3))) void*)dst, 16, 0, 0);
}

// ---------------------------------------------------------------------------
// Compaction: mark used vocab rows, scan to slots
// ---------------------------------------------------------------------------
__global__ void mark_used(const int* __restrict__ x, unsigned char* __restrict__ flags) {
    int i = blockIdx.x * 256 + threadIdx.x;
    if (i < NTOK) { int id = x[i]; if (id >= NSPEC) flags[id - NSPEC] = 1; }
}

__global__ void scan_compact(const unsigned char* __restrict__ flags,
                             int* __restrict__ slotmap, int* __restrict__ rowlist,
                             int* __restrict__ U) {
    __shared__ int psum[1024];
    int t = threadIdx.x;  // 0..1023
    int base = t * 32;
    int cnt = 0;
    for (int k = 0; k < 32; ++k) { int v = base + k; if (v < V_WORDS) cnt += flags[v]; }
    psum[t] = cnt;
    __syncthreads();
    for (int off = 1; off < 1024; off <<= 1) {
        int val = (t >= off) ? psum[t - off] : 0;
        __syncthreads();
        psum[t] += val;
        __syncthreads();
    }
    int excl = psum[t] - cnt;
    for (int k = 0; k < 32; ++k) {
        int v = base + k;
        if (v < V_WORDS) {
            slotmap[v] = excl;
            if (flags[v]) { rowlist[excl] = v; ++excl; }
        }
    }
    if (t == 1023) *U = psum[1023];
}

// ---------------------------------------------------------------------------
// EmbeddingBag(sum)+tanh, only for used rows; output bf16 per slot
// ---------------------------------------------------------------------------
__global__ void seg_sum_tanh(const int* __restrict__ ngram_ids,
                             const int* __restrict__ seg_ids,
                             const float* __restrict__ W,
                             const int* __restrict__ rowlist,
                             const int* __restrict__ Uptr,
                             short* __restrict__ langc) {   // [MAXU][128] bf16
    int b = blockIdx.x;
    if (b >= *Uptr) return;
    int v = rowlist[b];
    int t = threadIdx.x;  // 0..127
    int lo = 0, hi = TOTAL_NGRAMS;
    while (lo < hi) { int m = (lo + hi) >> 1; if (seg_ids[m] < v) lo = m + 1; else hi = m; }
    int start = lo;
    hi = TOTAL_NGRAMS;
    while (lo < hi) { int m = (lo + hi) >> 1; if (seg_ids[m] < v + 1) lo = m + 1; else hi = m; }
    int end = lo;
    float acc = 0.f;
    for (int j = start; j < end; ++j) {
        int id = ngram_ids[j];
        acc += W[(size_t)id * DIM + t];
    }
    langc[(size_t)b * DIM + t] = f2bf(tanhf(acc));
}

// ---------------------------------------------------------------------------
// latent fp32 -> bf16 + padded bf16 transpose
// ---------------------------------------------------------------------------
__global__ void conv_latent(const float* __restrict__ latent,  // [10000][128]
                            short* __restrict__ latbf,         // [10000][128]
                            short* __restrict__ latTbf) {      // [128][LT_STRIDE]
    __shared__ float tile[32][33];
    int n0 = blockIdx.x * 32;
    int d0 = blockIdx.y * 32;
    int tx = threadIdx.x;   // 0..31
    int ty = threadIdx.y;   // 0..7
    for (int k = 0; k < 32; k += 8) {
        int n = n0 + ty + k;
        float val = (n < LATENT) ? latent[(size_t)n * DIM + d0 + tx] : 0.f;
        tile[ty + k][tx] = val;
        if (n < LATENT) latbf[(size_t)n * DIM + d0 + tx] = f2bf(val);
    }
    __syncthreads();
    for (int k = 0; k < 32; k += 8) {
        int d = d0 + ty + k;
        int n = n0 + tx;
        latTbf[(size_t)d * LT_STRIDE + n] = (n < LATENT) ? f2bf(tile[tx][ty + k]) : (short)0;
    }
}

// ---------------------------------------------------------------------------
// Flash: Onum[slot] += sum_k exp(S) V ; Dsum[slot] += sum_k exp(S)
// grid = 64*KSPLIT blocks, 256 thr (4 waves x 32 q-rows). dbuf K/V staged via
// global_load_lds w/ pre-swizzled global source; one barrier per K-iter.
// ---------------------------------------------------------------------------
__global__ __launch_bounds__(256, 2)
void flash_latent(const short* __restrict__ langc,
                  const short* __restrict__ latbf,
                  const short* __restrict__ latTbf,
                  const int* __restrict__ Uptr,
                  float* __restrict__ Onum,    // [MAXU][128] f32 (zeroed)
                  float* __restrict__ Dsum) {  // [MAXU] f32 (zeroed)
    const int U = *Uptr;
    const int chunk = blockIdx.x >> 3;   // 0..63
    const int ks = blockIdx.x & 7;       // K-split id (aligns with XCD = bx%8)
    if (chunk * 128 >= U) return;

    __shared__ __align__(16) short Kl[2][BK * DIM];    // 2 x 16KB
    __shared__ __align__(16) short Vtl[2][DIM * BK];   // 2 x 16KB
    __shared__ __align__(16) short Pl[4][32 * BK];     // 4 x 4KB per-wave

    const int tid = threadIdx.x;
    const int w = tid >> 6, l = tid & 63, l16 = l & 15, g = l >> 4;
    const int rowbase = chunk * 128 + w * 32;

    // Q fragments (bf16 direct): lane holds Q[rowset r, row l16][c*32+g*8 ..+7]
    short8 qf[2][4];
#pragma unroll
    for (int r = 0; r < 2; ++r)
#pragma unroll
        for (int c = 0; c < 4; ++c)
            qf[r][c] = *reinterpret_cast<const short8*>(
                langc + (size_t)(rowbase + r * 16 + l16) * DIM + c * 32 + g * 8);

    f32x4 o[2][8];
#pragma unroll
    for (int r = 0; r < 2; ++r)
#pragma unroll
        for (int s = 0; s < 8; ++s) o[r][s] = (f32x4){0.f, 0.f, 0.f, 0.f};
    float lsum[2][4] = {{0.f, 0.f, 0.f, 0.f}, {0.f, 0.f, 0.f, 0.f}};

    const int kstart = ks * KCH;
    const int kend = (kstart + KCH < LATENT) ? (kstart + KCH) : LATENT;
    const int niter = (kend - kstart + BK - 1) / BK;

#define STAGE(KT, BUF)                                                                 \
    do {                                                                               \
        const int k0s = kstart + (KT) * BK;                                            \
        _Pragma("unroll")                                                              \
        for (int i = 0; i < 4; ++i) {                                                  \
            int c = (w * 4 + i) * 64 + l;                                              \
            int r = c >> 4, p = c & 15;                                                \
            int gk = k0s + r; if (gk > LATENT - 1) gk = LATENT - 1;                    \
            gl_lds16(latbf + (size_t)gk * DIM + ((p ^ (r & 7)) * 8),                   \
                     &Kl[BUF][(w * 4 + i) * 512]);                                     \
        }                                                                              \
        _Pragma("unroll")                                                              \
        for (int i = 0; i < 4; ++i) {                                                  \
            int c = (w * 4 + i) * 64 + l;                                              \
            int d = c >> 3, p = c & 7;                                                 \
            gl_lds16(latTbf + (size_t)d * LT_STRIDE + k0s + ((p ^ (d & 7)) * 8),       \
                     &Vtl[BUF][(w * 4 + i) * 512]);                                    \
        }                                                                              \
    } while (0)

    STAGE(0, 0);
    __syncthreads();
    int cur = 0;

    for (int kt = 0; kt < niter; ++kt) {
        if (kt + 1 < niter) STAGE(kt + 1, cur ^ 1);
        const int k0 = kstart + kt * BK;

        // S = Q * K^T  (B-frags shared by both rowsets)
        f32x4 s[2][4];
#pragma unroll
        for (int r = 0; r < 2; ++r)
#pragma unroll
            for (int t = 0; t < 4; ++t) s[r][t] = (f32x4){0.f, 0.f, 0.f, 0.f};
#pragma unroll
        for (int t = 0; t < 4; ++t) {
            int row = t * 16 + l16;
#pragma unroll
            for (int c = 0; c < 4; ++c) {
                short8 b = *reinterpret_cast<const short8*>(
                    &Kl[cur][row * DIM + (((c * 4 + g) ^ (row & 7)) * 8)]);
                s[0][t] = __builtin_amdgcn_mfma_f32_16x16x32_bf16(qf[0][c], b, s[0][t], 0, 0, 0);
                s[1][t] = __builtin_amdgcn_mfma_f32_16x16x32_bf16(qf[1][c], b, s[1][t], 0, 0, 0);
            }
        }

        // P = exp(S), row-sums, P -> per-wave LDS (swizzled)
#pragma unroll
        for (int t = 0; t < 4; ++t) {
            int kg = k0 + t * 16 + l16;
            bool valid = kg < kend;
#pragma unroll
            for (int r = 0; r < 2; ++r)
#pragma unroll
                for (int j = 0; j < 4; ++j) {
                    float p = valid ? __expf(s[r][t][j]) : 0.f;
                    lsum[r][j] += p;
                    int prow = r * 16 + g * 4 + j;
                    int e = t * 16 + l16;
                    Pl[w][prow * BK + (((e >> 3) ^ (prow & 7)) * 8) + (e & 7)] = f2bf(p);
                }
        }

        // O += P * V  (B-frags shared by both rowsets)
        short8 pa[2][2];
#pragma unroll
        for (int r = 0; r < 2; ++r)
#pragma unroll
            for (int c2 = 0; c2 < 2; ++c2) {
                int prow = r * 16 + l16;
                pa[r][c2] = *reinterpret_cast<const short8*>(
                    &Pl[w][prow * BK + (((c2 * 4 + g) ^ (prow & 7)) * 8)]);
            }
#pragma unroll
        for (int sub = 0; sub < 8; ++sub) {
            int drow = sub * 16 + l16;
#pragma unroll
            for (int c2 = 0; c2 < 2; ++c2) {
                short8 b = *reinterpret_cast<const short8*>(
                    &Vtl[cur][drow * BK + (((c2 * 4 + g) ^ (drow & 7)) * 8)]);
                o[0][sub] = __builtin_amdgcn_mfma_f32_16x16x32_bf16(pa[0][c2], b, o[0][sub], 0, 0, 0);
                o[1][sub] = __builtin_amdgcn_mfma_f32_16x16x32_bf16(pa[1][c2], b, o[1][sub], 0, 0, 0);
            }
        }
        __syncthreads();   // drains vmcnt (stage kt+1 done) + all reads of buf[cur] done
        cur ^= 1;
    }

    // reduce lsum across the 16 lanes of each row-group
#pragma unroll
    for (int r = 0; r < 2; ++r)
#pragma unroll
        for (int j = 0; j < 4; ++j) {
            float v = lsum[r][j];
            v += __shfl_xor(v, 1, 64);
            v += __shfl_xor(v, 2, 64);
            v += __shfl_xor(v, 4, 64);
            v += __shfl_xor(v, 8, 64);
            lsum[r][j] = v;
        }
    if (l16 == 0) {
#pragma unroll
        for (int r = 0; r < 2; ++r)
#pragma unroll
            for (int j = 0; j < 4; ++j)
                atomicAdd(&Dsum[rowbase + r * 16 + g * 4 + j], lsum[r][j]);
    }
#pragma unroll
    for (int sub = 0; sub < 8; ++sub)
#pragma unroll
        for (int r = 0; r < 2; ++r)
#pragma unroll
            for (int j = 0; j < 4; ++j) {
                int row = rowbase + r * 16 + g * 4 + j;
                atomicAdd(&Onum[(size_t)row * DIM + sub * 16 + l16], o[r][sub][j]);
            }
}

// ---------------------------------------------------------------------------
// Final gather: out[i] = special OR langc[slot] + Onum[slot]/Dsum[slot]
// ---------------------------------------------------------------------------
__global__ void gather_out(const int* __restrict__ x,
                           const short* __restrict__ langc,
                           const int* __restrict__ slotmap,
                           const float* __restrict__ Onum,
                           const float* __restrict__ Dsum,
                           const float* __restrict__ special,
                           float* __restrict__ out) {
    int i = blockIdx.x;   // 0..8191
    int t = threadIdx.x;  // 0..127
    int id = x[i];
    float v;
    if (id < NSPEC) {
        v = special[(size_t)id * DIM + t];
    } else {
        int s = slotmap[id - NSPEC];
        v = bf2f(langc[(size_t)s * DIM + t]) + Onum[(size_t)s * DIM + t] / Dsum[s];
    }
    out[(size_t)i * DIM + t] = v;
}

// ---------------------------------------------------------------------------
extern "C" void kernel_launch(void* const* d_in, const int* in_sizes, int n_in,
                              void* d_out, int out_size, void* d_ws, size_t ws_size,
                              hipStream_t stream) {
    const int*   x        = (const int*)d_in[0];
    const int*   ngram_id = (const int*)d_in[1];
    const int*   seg_id   = (const int*)d_in[2];
    const float* W        = (const float*)d_in[3];   // [32001,128]
    const float* latent   = (const float*)d_in[4];   // [10000,128]
    const float* special  = (const float*)d_in[5];   // [4,128]
    float* out = (float*)d_out;

    // workspace layout (~11.7 MB total)
    char* ws = (char*)d_ws;
    unsigned char* flags = (unsigned char*)ws;             // 32,000 B
    int*   slotmap = (int*)(ws + 32768);                   // 128,000 B
    int*   rowlist = (int*)(ws + 160768);                  // 32,768 B
    int*   Uptr    = (int*)(ws + 193536);                  // 4 B
    short* langc   = (short*)(ws + 194048);                // 2,097,152 B
    short* latbf   = (short*)(ws + 2291200);               // 2,560,000 B
    short* latTbf  = (short*)(ws + 4851200);               // 2,588,672 B
    float* Onum    = (float*)(ws + 7439872);               // 4,194,304 B
    float* Dsum    = (float*)(ws + 11634176);              // 32,768 B

    hipMemsetAsync(flags, 0, 32000, stream);
    hipMemsetAsync(Onum, 0, 4194304 + 32768, stream);      // Onum + Dsum contiguous

    mark_used<<<NTOK / 256, 256, 0, stream>>>(x, flags);
    scan_compact<<<1, 1024, 0, stream>>>(flags, slotmap, rowlist, Uptr);
    seg_sum_tanh<<<MAXU, 128, 0, stream>>>(ngram_id, seg_id, W, rowlist, Uptr, langc);
    conv_latent<<<dim3(LT_STRIDE / 32, DIM / 32), dim3(32, 8), 0, stream>>>(latent, latbf, latTbf);
    flash_latent<<<64 * KSPLIT, 256, 0, stream>>>(langc, latbf, latTbf, Uptr, Onum, Dsum);
    gather_out<<<NTOK, 128, 0, stream>>>(x, langc, slotmap, Onum, Dsum, special, out);
}

// Round 3
// 134.216 us; speedup vs baseline: 5.0433x; 1.3219x over previous
//
#include <hip/hip_runtime.h>
#include <hip/hip_bf16.h>

// Problem constants
#define V_WORDS 32000
#define NSPEC 4
#define DIM 128
#define LATENT 10000
#define LT_STRIDE 10112      // padded col count for latTbf rows
#define TOTAL_NGRAMS 704000
#define NTOK 8192
#define MAXU 8192
#define KSPLIT 8
#define KCH 1280
#define BK 64

typedef __attribute__((ext_vector_type(4))) float f32x4;
typedef __attribute__((ext_vector_type(8))) short short8;
typedef __attribute__((ext_vector_type(2))) short short2v;

__device__ __forceinline__ short f2bf(float f) {
    __hip_bfloat16 h = __float2bfloat16(f);
    return *reinterpret_cast<short*>(&h);
}
__device__ __forceinline__ float bf2f(short s) {
    unsigned u = ((unsigned)(unsigned short)s) << 16;
    return __uint_as_float(u);
}

// async global->LDS 16B (linear LDS dest = uniform base + lane*16)
__device__ __forceinline__ void gl_lds16(const short* src, short* dst) {
    __builtin_amdgcn_global_load_lds(
        (const __attribute__((address_space(1))) void*)src,
        (__attribute__((address_space(3))) void*)dst, 16, 0, 0);
}

// ---------------------------------------------------------------------------
// segment boundary precompute: bounds[v] = lower_bound(seg_ids, v)
// ---------------------------------------------------------------------------
__global__ void seg_bounds(const int* __restrict__ seg_ids, int* __restrict__ bounds) {
    int i = blockIdx.x * 256 + threadIdx.x;
    if (i >= TOTAL_NGRAMS) return;
    int cur = seg_ids[i];
    int prev = (i == 0) ? -1 : seg_ids[i - 1];
    for (int v = prev + 1; v <= cur; ++v) bounds[v] = i;
    if (i == TOTAL_NGRAMS - 1)
        for (int v = cur + 1; v <= V_WORDS; ++v) bounds[v] = TOTAL_NGRAMS;
}

// ---------------------------------------------------------------------------
// Compaction: mark used vocab rows, scan to slots
// ---------------------------------------------------------------------------
__global__ void mark_used(const int* __restrict__ x, unsigned char* __restrict__ flags) {
    int i = blockIdx.x * 256 + threadIdx.x;
    if (i < NTOK) { int id = x[i]; if (id >= NSPEC) flags[id - NSPEC] = 1; }
}

__device__ __forceinline__ int bytesum(unsigned d) {
    return (int)(((d & 0x01010101u) * 0x01010101u) >> 24);
}

__global__ void scan_compact(const unsigned char* __restrict__ flags,
                             int* __restrict__ slotmap, int* __restrict__ rowlist,
                             int* __restrict__ U) {
    __shared__ int psum[1024];
    int t = threadIdx.x;  // 0..1023 ; valid flag range iff t < 1000 (32 bytes each)
    uint4 a = {0, 0, 0, 0}, b = {0, 0, 0, 0};
    int cnt = 0;
    if (t < 1000) {
        const uint4* f4 = reinterpret_cast<const uint4*>(flags);
        a = f4[t * 2];
        b = f4[t * 2 + 1];
        cnt = bytesum(a.x) + bytesum(a.y) + bytesum(a.z) + bytesum(a.w) +
              bytesum(b.x) + bytesum(b.y) + bytesum(b.z) + bytesum(b.w);
    }
    psum[t] = cnt;
    __syncthreads();
    for (int off = 1; off < 1024; off <<= 1) {
        int val = (t >= off) ? psum[t - off] : 0;
        __syncthreads();
        psum[t] += val;
        __syncthreads();
    }
    int excl = psum[t] - cnt;
    if (t < 1000) {
        unsigned v8[8] = {a.x, a.y, a.z, a.w, b.x, b.y, b.z, b.w};
        int base = t * 32;
#pragma unroll
        for (int k = 0; k < 32; ++k) {
            int fv = (int)((v8[k >> 2] >> ((k & 3) * 8)) & 1u);
            slotmap[base + k] = excl;
            if (fv) { rowlist[excl] = base + k; ++excl; }
        }
    }
    if (t == 1023) *U = psum[1023];
}

// ---------------------------------------------------------------------------
// EmbeddingBag(sum)+tanh for used rows; wave-per-row, float2 lanes
// ---------------------------------------------------------------------------
__global__ __launch_bounds__(256)
void seg_sum_tanh(const int* __restrict__ ngram_ids,
                  const int* __restrict__ bounds,
                  const float* __restrict__ W,
                  const int* __restrict__ rowlist,
                  const int* __restrict__ Uptr,
                  short* __restrict__ langc) {   // [MAXU][128] bf16
    int slot = blockIdx.x * 4 + (threadIdx.x >> 6);
    if (slot >= *Uptr) return;
    int v = rowlist[slot];
    int l = threadIdx.x & 63;
    int start = bounds[v], end = bounds[v + 1];
    float ax = 0.f, ay = 0.f;
    for (int j = start; j < end; ++j) {
        int id = ngram_ids[j];   // wave-uniform -> scalar broadcast
        float2 row = *reinterpret_cast<const float2*>(W + (size_t)id * DIM + l * 2);
        ax += row.x; ay += row.y;
    }
    short2v o;
    o.x = f2bf(tanhf(ax));
    o.y = f2bf(tanhf(ay));
    *reinterpret_cast<short2v*>(langc + (size_t)slot * DIM + l * 2) = o;
}

// ---------------------------------------------------------------------------
// latent fp32 -> bf16 + padded bf16 transpose
// ---------------------------------------------------------------------------
__global__ void conv_latent(const float* __restrict__ latent,  // [10000][128]
                            short* __restrict__ latbf,         // [10000][128]
                            short* __restrict__ latTbf) {      // [128][LT_STRIDE]
    __shared__ float tile[32][33];
    int n0 = blockIdx.x * 32;
    int d0 = blockIdx.y * 32;
    int tx = threadIdx.x;   // 0..31
    int ty = threadIdx.y;   // 0..7
    for (int k = 0; k < 32; k += 8) {
        int n = n0 + ty + k;
        float val = (n < LATENT) ? latent[(size_t)n * DIM + d0 + tx] : 0.f;
        tile[ty + k][tx] = val;
        if (n < LATENT) latbf[(size_t)n * DIM + d0 + tx] = f2bf(val);
    }
    __syncthreads();
    for (int k = 0; k < 32; k += 8) {
        int d = d0 + ty + k;
        int n = n0 + tx;
        latTbf[(size_t)d * LT_STRIDE + n] = (n < LATENT) ? f2bf(tile[tx][ty + k]) : (short)0;
    }
}

// ---------------------------------------------------------------------------
// Flash: Onum[slot] += sum_k exp(S) V ; Dsum[slot] += sum_k exp(S)
// counted-vmcnt double-barrier pipeline: prefetch stays in flight across the
// first barrier (vmcnt(8) = next tile's 8 loads outstanding); second barrier
// is the read-done fence before the buffer is re-staged.
// ---------------------------------------------------------------------------
__global__ __launch_bounds__(256, 2)
void flash_latent(const short* __restrict__ langc,
                  const short* __restrict__ latbf,
                  const short* __restrict__ latTbf,
                  const int* __restrict__ Uptr,
                  float* __restrict__ Onum,    // [MAXU][128] f32 (zeroed)
                  float* __restrict__ Dsum) {  // [MAXU] f32 (zeroed)
    const int U = *Uptr;
    const int chunk = blockIdx.x >> 3;   // 0..63
    const int ks = blockIdx.x & 7;       // K-split id (aligns with XCD = bx%8)
    if (chunk * 128 >= U) return;

    __shared__ __align__(16) short Kl[2][BK * DIM];    // 2 x 16KB
    __shared__ __align__(16) short Vtl[2][DIM * BK];   // 2 x 16KB
    __shared__ __align__(16) short Pl[4][32 * BK];     // 4 x 4KB per-wave

    const int tid = threadIdx.x;
    const int w = tid >> 6, l = tid & 63, l16 = l & 15, g = l >> 4;
    const int rowbase = chunk * 128 + w * 32;

    // Q fragments: lane holds Q[rowset r, row l16][c*32+g*8 ..+7]
    short8 qf[2][4];
#pragma unroll
    for (int r = 0; r < 2; ++r)
#pragma unroll
        for (int c = 0; c < 4; ++c)
            qf[r][c] = *reinterpret_cast<const short8*>(
                langc + (size_t)(rowbase + r * 16 + l16) * DIM + c * 32 + g * 8);

    f32x4 o[2][8];
#pragma unroll
    for (int r = 0; r < 2; ++r)
#pragma unroll
        for (int s = 0; s < 8; ++s) o[r][s] = (f32x4){0.f, 0.f, 0.f, 0.f};
    float lsum[2][4] = {{0.f, 0.f, 0.f, 0.f}, {0.f, 0.f, 0.f, 0.f}};

    const int kstart = ks * KCH;
    const int kend = (kstart + KCH < LATENT) ? (kstart + KCH) : LATENT;
    const int niter = (kend - kstart + BK - 1) / BK;

#define STAGE(KT, BUF)                                                                 \
    do {                                                                               \
        const int k0s = kstart + (KT) * BK;                                            \
        _Pragma("unroll")                                                              \
        for (int i = 0; i < 4; ++i) {                                                  \
            int c = (w * 4 + i) * 64 + l;                                              \
            int r = c >> 4, p = c & 15;                                                \
            int gk = k0s + r; if (gk > LATENT - 1) gk = LATENT - 1;                    \
            gl_lds16(latbf + (size_t)gk * DIM + ((p ^ (r & 7)) * 8),                   \
                     &Kl[BUF][(w * 4 + i) * 512]);                                     \
        }                                                                              \
        _Pragma("unroll")                                                              \
        for (int i = 0; i < 4; ++i) {                                                  \
            int c = (w * 4 + i) * 64 + l;                                              \
            int d = c >> 3, p = c & 7;                                                 \
            gl_lds16(latTbf + (size_t)d * LT_STRIDE + k0s + ((p ^ (d & 7)) * 8),       \
                     &Vtl[BUF][(w * 4 + i) * 512]);                                    \
        }                                                                              \
    } while (0)

    STAGE(0, 0);
    int cur = 0;

    for (int kt = 0; kt < niter; ++kt) {
        if (kt + 1 < niter) {
            STAGE(kt + 1, cur ^ 1);
            asm volatile("s_waitcnt vmcnt(8)" ::: "memory");   // tile kt landed (this wave)
        } else {
            asm volatile("s_waitcnt vmcnt(0)" ::: "memory");
        }
        __builtin_amdgcn_s_barrier();          // all waves' tile-kt loads landed
        __builtin_amdgcn_sched_barrier(0);

        const int k0 = kstart + kt * BK;

        // S = Q * K^T  (B-frags shared by both rowsets)
        f32x4 s[2][4];
#pragma unroll
        for (int r = 0; r < 2; ++r)
#pragma unroll
            for (int t = 0; t < 4; ++t) s[r][t] = (f32x4){0.f, 0.f, 0.f, 0.f};
#pragma unroll
        for (int t = 0; t < 4; ++t) {
            int row = t * 16 + l16;
#pragma unroll
            for (int c = 0; c < 4; ++c) {
                short8 b = *reinterpret_cast<const short8*>(
                    &Kl[cur][row * DIM + (((c * 4 + g) ^ (row & 7)) * 8)]);
                s[0][t] = __builtin_amdgcn_mfma_f32_16x16x32_bf16(qf[0][c], b, s[0][t], 0, 0, 0);
                s[1][t] = __builtin_amdgcn_mfma_f32_16x16x32_bf16(qf[1][c], b, s[1][t], 0, 0, 0);
            }
        }

        // P = exp(S), row-sums, P -> per-wave LDS (swizzled)
#pragma unroll
        for (int t = 0; t < 4; ++t) {
            int kg = k0 + t * 16 + l16;
            bool valid = kg < kend;
#pragma unroll
            for (int r = 0; r < 2; ++r)
#pragma unroll
                for (int j = 0; j < 4; ++j) {
                    float p = valid ? __expf(s[r][t][j]) : 0.f;
                    lsum[r][j] += p;
                    int prow = r * 16 + g * 4 + j;
                    int e = t * 16 + l16;
                    Pl[w][prow * BK + (((e >> 3) ^ (prow & 7)) * 8) + (e & 7)] = f2bf(p);
                }
        }

        // O += P * V  (B-frags shared by both rowsets)
        short8 pa[2][2];
#pragma unroll
        for (int r = 0; r < 2; ++r)
#pragma unroll
            for (int c2 = 0; c2 < 2; ++c2) {
                int prow = r * 16 + l16;
                pa[r][c2] = *reinterpret_cast<const short8*>(
                    &Pl[w][prow * BK + (((c2 * 4 + g) ^ (prow & 7)) * 8)]);
            }
#pragma unroll
        for (int sub = 0; sub < 8; ++sub) {
            int drow = sub * 16 + l16;
#pragma unroll
            for (int c2 = 0; c2 < 2; ++c2) {
                short8 b = *reinterpret_cast<const short8*>(
                    &Vtl[cur][drow * BK + (((c2 * 4 + g) ^ (drow & 7)) * 8)]);
                o[0][sub] = __builtin_amdgcn_mfma_f32_16x16x32_bf16(pa[0][c2], b, o[0][sub], 0, 0, 0);
                o[1][sub] = __builtin_amdgcn_mfma_f32_16x16x32_bf16(pa[1][c2], b, o[1][sub], 0, 0, 0);
            }
        }

        __builtin_amdgcn_sched_barrier(0);
        __builtin_amdgcn_s_barrier();          // read-done fence for buf[cur]
        cur ^= 1;
    }

    // reduce lsum across the 16 lanes of each row-group
#pragma unroll
    for (int r = 0; r < 2; ++r)
#pragma unroll
        for (int j = 0; j < 4; ++j) {
            float v = lsum[r][j];
            v += __shfl_xor(v, 1, 64);
            v += __shfl_xor(v, 2, 64);
            v += __shfl_xor(v, 4, 64);
            v += __shfl_xor(v, 8, 64);
            lsum[r][j] = v;
        }
    if (l16 == 0) {
#pragma unroll
        for (int r = 0; r < 2; ++r)
#pragma unroll
            for (int j = 0; j < 4; ++j)
                atomicAdd(&Dsum[rowbase + r * 16 + g * 4 + j], lsum[r][j]);
    }
#pragma unroll
    for (int sub = 0; sub < 8; ++sub)
#pragma unroll
        for (int r = 0; r < 2; ++r)
#pragma unroll
            for (int j = 0; j < 4; ++j) {
                int row = rowbase + r * 16 + g * 4 + j;
                atomicAdd(&Onum[(size_t)row * DIM + sub * 16 + l16], o[r][sub][j]);
            }
}

// ---------------------------------------------------------------------------
// Final gather: out[i] = special OR langc[slot] + Onum[slot]/Dsum[slot]
// ---------------------------------------------------------------------------
__global__ void gather_out(const int* __restrict__ x,
                           const short* __restrict__ langc,
                           const int* __restrict__ slotmap,
                           const float* __restrict__ Onum,
                           const float* __restrict__ Dsum,
                           const float* __restrict__ special,
                           float* __restrict__ out) {
    int i = blockIdx.x;   // 0..8191
    int t = threadIdx.x;  // 0..127
    int id = x[i];
    float v;
    if (id < NSPEC) {
        v = special[(size_t)id * DIM + t];
    } else {
        int s = slotmap[id - NSPEC];
        v = bf2f(langc[(size_t)s * DIM + t]) + Onum[(size_t)s * DIM + t] / Dsum[s];
    }
    out[(size_t)i * DIM + t] = v;
}

// ---------------------------------------------------------------------------
extern "C" void kernel_launch(void* const* d_in, const int* in_sizes, int n_in,
                              void* d_out, int out_size, void* d_ws, size_t ws_size,
                              hipStream_t stream) {
    const int*   x        = (const int*)d_in[0];
    const int*   ngram_id = (const int*)d_in[1];
    const int*   seg_id   = (const int*)d_in[2];
    const float* W        = (const float*)d_in[3];   // [32001,128]
    const float* latent   = (const float*)d_in[4];   // [10000,128]
    const float* special  = (const float*)d_in[5];   // [4,128]
    float* out = (float*)d_out;

    // workspace layout (~11.8 MB total); [Onum|Dsum|flags] contiguous -> 1 memset
    char* ws = (char*)d_ws;
    float* Onum    = (float*)(ws + 0);                 // 4,194,304 B
    float* Dsum    = (float*)(ws + 4194304);           //    32,768 B
    unsigned char* flags = (unsigned char*)(ws + 4227072);  // 32,768 B (32000 used)
    int*   slotmap = (int*)(ws + 4259840);             //   128,256 B
    int*   rowlist = (int*)(ws + 4388096);             //    32,768 B
    int*   Uptr    = (int*)(ws + 4420864);             //       256 B
    int*   bounds  = (int*)(ws + 4421120);             //   128,256 B (32001 used)
    short* langc   = (short*)(ws + 4549376);           // 2,097,152 B
    short* latbf   = (short*)(ws + 6646528);           // 2,560,000 B
    short* latTbf  = (short*)(ws + 9206528);           // 2,588,672 B -> end 11,795,200

    hipMemsetAsync(ws, 0, 4259840, stream);            // Onum + Dsum + flags

    seg_bounds<<<(TOTAL_NGRAMS + 255) / 256, 256, 0, stream>>>(seg_id, bounds);
    mark_used<<<NTOK / 256, 256, 0, stream>>>(x, flags);
    scan_compact<<<1, 1024, 0, stream>>>(flags, slotmap, rowlist, Uptr);
    seg_sum_tanh<<<MAXU / 4, 256, 0, stream>>>(ngram_id, bounds, W, rowlist, Uptr, langc);
    conv_latent<<<dim3(LT_STRIDE / 32, DIM / 32), dim3(32, 8), 0, stream>>>(latent, latbf, latTbf);
    flash_latent<<<64 * KSPLIT, 256, 0, stream>>>(langc, latbf, latTbf, Uptr, Onum, Dsum);
    gather_out<<<NTOK, 128, 0, stream>>>(x, langc, slotmap, Onum, Dsum, special, out);
}

// Round 4
// 121.106 us; speedup vs baseline: 5.5892x; 1.1083x over previous
//
#include <hip/hip_runtime.h>
#include <hip/hip_bf16.h>

// Problem constants
#define V_WORDS 32000
#define NSPEC 4
#define DIM 128
#define LATENT 10000
#define LT_STRIDE 10112      // padded fp8 V^T row length (bytes)
#define TOTAL_NGRAMS 704000
#define NTOK 8192
#define MAXU 8192
#define KSPLIT 8
#define KCH 1280
#define BK 64
#define SEG_BLOCKS 2048      // MAXU/4
#define BOUND_BLOCKS 2750    // 704000/256
#define CONV_BX 316          // LT_STRIDE/32
#define CONV_BY 4            // 128/32

typedef __attribute__((ext_vector_type(4))) float f32x4;
typedef __attribute__((ext_vector_type(2))) short short2v;

__device__ __forceinline__ short f2bf(float f) {
    __hip_bfloat16 h = __float2bfloat16(f);
    return *reinterpret_cast<short*>(&h);
}
__device__ __forceinline__ float bf2f(short s) {
    unsigned u = ((unsigned)(unsigned short)s) << 16;
    return __uint_as_float(u);
}

// async global->LDS 16B (LDS dest = wave-uniform base + lane*16)
__device__ __forceinline__ void gl_lds16(const void* src, void* dst) {
    __builtin_amdgcn_global_load_lds(
        (const __attribute__((address_space(1))) void*)src,
        (__attribute__((address_space(3))) void*)dst, 16, 0, 0);
}

// ---------------------------------------------------------------------------
// prep: seg bounds (blocks 0..2749) + mark used flags (blocks 2750..2781)
// ---------------------------------------------------------------------------
__global__ void prep(const int* __restrict__ x, const int* __restrict__ seg_ids,
                     unsigned char* __restrict__ flags, int* __restrict__ bounds) {
    int b = blockIdx.x;
    int t = threadIdx.x;
    if (b < BOUND_BLOCKS) {
        int i = b * 256 + t;
        int cur = seg_ids[i];
        int prev = (i == 0) ? -1 : seg_ids[i - 1];
        for (int v = prev + 1; v <= cur; ++v) bounds[v] = i;
        if (i == TOTAL_NGRAMS - 1)
            for (int v = cur + 1; v <= V_WORDS; ++v) bounds[v] = TOTAL_NGRAMS;
    } else {
        int i = (b - BOUND_BLOCKS) * 256 + t;
        if (i < NTOK) { int id = x[i]; if (id >= NSPEC) flags[id - NSPEC] = 1; }
    }
}

__device__ __forceinline__ int bytesum(unsigned d) {
    return (int)(((d & 0x01010101u) * 0x01010101u) >> 24);
}

__global__ void scan_compact(const unsigned char* __restrict__ flags,
                             int* __restrict__ slotmap, int* __restrict__ rowlist,
                             int* __restrict__ U) {
    __shared__ int psum[1024];
    int t = threadIdx.x;
    uint4 a = {0, 0, 0, 0}, b = {0, 0, 0, 0};
    int cnt = 0;
    if (t < 1000) {
        const uint4* f4 = reinterpret_cast<const uint4*>(flags);
        a = f4[t * 2];
        b = f4[t * 2 + 1];
        cnt = bytesum(a.x) + bytesum(a.y) + bytesum(a.z) + bytesum(a.w) +
              bytesum(b.x) + bytesum(b.y) + bytesum(b.z) + bytesum(b.w);
    }
    psum[t] = cnt;
    __syncthreads();
    for (int off = 1; off < 1024; off <<= 1) {
        int val = (t >= off) ? psum[t - off] : 0;
        __syncthreads();
        psum[t] += val;
        __syncthreads();
    }
    int excl = psum[t] - cnt;
    if (t < 1000) {
        unsigned v8[8] = {a.x, a.y, a.z, a.w, b.x, b.y, b.z, b.w};
        int base = t * 32;
#pragma unroll
        for (int k = 0; k < 32; ++k) {
            int fv = (int)((v8[k >> 2] >> ((k & 3) * 8)) & 1u);
            slotmap[base + k] = excl;
            if (fv) { rowlist[excl] = base + k; ++excl; }
        }
    }
    if (t == 1023) *U = psum[1023];
}

// ---------------------------------------------------------------------------
// seg_conv: blocks 0..2047 = EmbeddingBag+tanh (bf16 + fp8 out);
//           blocks 2048..  = latent fp8 convert + fp8 transpose
// ---------------------------------------------------------------------------
__global__ __launch_bounds__(256)
void seg_conv(const int* __restrict__ ngram_ids, const int* __restrict__ bounds,
              const float* __restrict__ W, const int* __restrict__ rowlist,
              const int* __restrict__ Uptr, short* __restrict__ langc,
              unsigned char* __restrict__ langq,
              const float* __restrict__ latent,
              unsigned char* __restrict__ latf8, unsigned char* __restrict__ latT8) {
    __shared__ float tile[32][36];
    int t = threadIdx.x;
    if (blockIdx.x < SEG_BLOCKS) {
        int slot = blockIdx.x * 4 + (t >> 6);
        if (slot >= *Uptr) return;
        int v = rowlist[slot];
        int l = t & 63;
        int start = bounds[v], end = bounds[v + 1];
        float ax = 0.f, ay = 0.f;
        for (int j = start; j < end; ++j) {
            int id = ngram_ids[j];
            float2 row = *reinterpret_cast<const float2*>(W + (size_t)id * DIM + l * 2);
            ax += row.x; ay += row.y;
        }
        float tx = tanhf(ax), ty = tanhf(ay);
        short2v o; o.x = f2bf(tx); o.y = f2bf(ty);
        *reinterpret_cast<short2v*>(langc + (size_t)slot * DIM + l * 2) = o;
        int pk = __builtin_amdgcn_cvt_pk_fp8_f32(tx, ty, 0, false);
        *reinterpret_cast<unsigned short*>(langq + (size_t)slot * DIM + l * 2) =
            (unsigned short)(pk & 0xFFFF);
    } else {
        int bx = blockIdx.x - SEG_BLOCKS;
        int n0 = (bx % CONV_BX) * 32;
        int d0 = (bx / CONV_BX) * 32;
        // phase A: load 32n x 32d tile (float4/thread), emit latf8
        int nl = t >> 3, dq = t & 7;
        int n = n0 + nl, d = d0 + dq * 4;
        float4 v = {0.f, 0.f, 0.f, 0.f};
        if (n < LATENT) v = *reinterpret_cast<const float4*>(latent + (size_t)n * DIM + d);
        *reinterpret_cast<float4*>(&tile[nl][dq * 4]) = v;
        if (n < LATENT) {
            int pk = __builtin_amdgcn_cvt_pk_fp8_f32(v.x, v.y, 0, false);
            pk = __builtin_amdgcn_cvt_pk_fp8_f32(v.z, v.w, pk, true);
            *reinterpret_cast<unsigned*>(latf8 + (size_t)n * DIM + d) = (unsigned)pk;
        }
        __syncthreads();
        // phase B: transposed fp8 writes (n-pairs)
#pragma unroll
        for (int u = 0; u < 2; ++u) {
            int it = t + u * 256;
            int dl = it >> 4, np = it & 15;
            float v0 = tile[np * 2][dl], v1 = tile[np * 2 + 1][dl];
            int pk = __builtin_amdgcn_cvt_pk_fp8_f32(v0, v1, 0, false);
            *reinterpret_cast<unsigned short*>(
                latT8 + (size_t)(d0 + dl) * LT_STRIDE + n0 + np * 2) =
                (unsigned short)(pk & 0xFFFF);
        }
    }
}

// ---------------------------------------------------------------------------
// Flash (fp8): Onum += sum_k exp(S)V ; Dsum += sum_k exp(S)
// Swapped QK^T (mfma(K,Q) -> S^T): P is lane-local per q-row; packed to fp8
// in-register via cvt_pk_fp8 + permlane{32,16}_swap (no P LDS round-trip).
// K/V tiles fp8 in LDS, 16B-XOR-swizzled, staged via global_load_lds w/
// pre-swizzled source; double-buffered, counted vmcnt.
// ---------------------------------------------------------------------------
__global__ __launch_bounds__(256, 2)
void flash_latent(const unsigned char* __restrict__ langq,  // fp8 [MAXU][128]
                  const unsigned char* __restrict__ latf8,  // fp8 [LATENT][128]
                  const unsigned char* __restrict__ latT8,  // fp8 [128][LT_STRIDE]
                  const int* __restrict__ Uptr,
                  float* __restrict__ Onum,    // [MAXU][128] f32 (zeroed)
                  float* __restrict__ Dsum) {  // [MAXU] f32 (zeroed)
    const int U = *Uptr;
    const int chunk = blockIdx.x >> 3;
    const int ks = blockIdx.x & 7;       // K-split (aligns with XCD)
    if (chunk * 128 >= U) return;

    __shared__ __align__(16) unsigned char Kl[2][BK * DIM];   // 2 x 8KB
    __shared__ __align__(16) unsigned char Vl[2][DIM * BK];   // 2 x 8KB

    const int tid = threadIdx.x;
    const int w = tid >> 6, l = tid & 63, l16 = l & 15, g = l >> 4;
    const int g1 = g >> 1, g0 = g & 1;
    const int rowbase = chunk * 128 + w * 32;

    // Q fp8 frags: lane holds Q[rowset r, row l16][c*32 + g*8 + 0..7]
    long qf[2][4];
#pragma unroll
    for (int r = 0; r < 2; ++r)
#pragma unroll
        for (int c = 0; c < 4; ++c)
            qf[r][c] = *reinterpret_cast<const long*>(
                langq + (size_t)(rowbase + r * 16 + l16) * DIM + c * 32 + g * 8);

    f32x4 o[2][8];
#pragma unroll
    for (int r = 0; r < 2; ++r)
#pragma unroll
        for (int s = 0; s < 8; ++s) o[r][s] = (f32x4){0.f, 0.f, 0.f, 0.f};
    float lsum[2] = {0.f, 0.f};

    const int kstart = ks * KCH;
    const int kend = (kstart + KCH < LATENT) ? (kstart + KCH) : LATENT;
    const int niter = (kend - kstart + BK - 1) / BK;

#define STAGE(KT, BUF)                                                              \
    do {                                                                            \
        const int k0s = kstart + (KT) * BK;                                         \
        _Pragma("unroll")                                                           \
        for (int i = 0; i < 2; ++i) {                                               \
            int c = (w * 2 + i) * 64 + l;                                           \
            int rr = c >> 3, s16 = c & 7;                                           \
            int gk = k0s + rr; if (gk > LATENT - 1) gk = LATENT - 1;                \
            gl_lds16(latf8 + (size_t)gk * DIM + ((s16 ^ (rr & 7)) * 16),            \
                     &Kl[BUF][(w * 2 + i) * 1024]);                                 \
        }                                                                           \
        _Pragma("unroll")                                                           \
        for (int i = 0; i < 2; ++i) {                                               \
            int c = (w * 2 + i) * 64 + l;                                           \
            int dd = c >> 2, s16 = c & 3;                                           \
            gl_lds16(latT8 + (size_t)dd * LT_STRIDE + k0s + ((s16 ^ (dd & 3)) * 16),\
                     &Vl[BUF][(w * 2 + i) * 1024]);                                 \
        }                                                                           \
    } while (0)

    STAGE(0, 0);
    int cur = 0;

    for (int kt = 0; kt < niter; ++kt) {
        if (kt + 1 < niter) {
            STAGE(kt + 1, cur ^ 1);
            asm volatile("s_waitcnt vmcnt(4)" ::: "memory");
        } else {
            asm volatile("s_waitcnt vmcnt(0)" ::: "memory");
        }
        __builtin_amdgcn_s_barrier();
        __builtin_amdgcn_sched_barrier(0);

        const int k0 = kstart + kt * BK;
        const int rem = kend - k0;

        // S^T = K * Q^T  (K A-frags shared by both rowsets)
        f32x4 s[2][4];
#pragma unroll
        for (int r = 0; r < 2; ++r)
#pragma unroll
            for (int t = 0; t < 4; ++t) s[r][t] = (f32x4){0.f, 0.f, 0.f, 0.f};
#pragma unroll
        for (int t = 0; t < 4; ++t) {
#pragma unroll
            for (int c = 0; c < 4; ++c) {
                long af = *reinterpret_cast<const long*>(
                    &Kl[cur][(t * 16 + l16) * 128 + (((c * 2 + g1) ^ (l16 & 7)) * 16) + g0 * 8]);
                s[0][t] = __builtin_amdgcn_mfma_f32_16x16x32_fp8_fp8(af, qf[0][c], s[0][t], 0, 0, 0);
                s[1][t] = __builtin_amdgcn_mfma_f32_16x16x32_fp8_fp8(af, qf[1][c], s[1][t], 0, 0, 0);
            }
        }

        // P = exp(S) lane-local (k = t*16 + g*4 + j, q-row = l16); pack fp8;
        // permlane swaps assemble PV A-frags (k 8g..8g+7 per tile)
        long pa[2][2];
#pragma unroll
        for (int r = 0; r < 2; ++r) {
            int q[4];
            if (rem >= BK) {
#pragma unroll
                for (int t = 0; t < 4; ++t) {
                    float p0 = __expf(s[r][t][0]), p1 = __expf(s[r][t][1]);
                    float p2 = __expf(s[r][t][2]), p3 = __expf(s[r][t][3]);
                    lsum[r] += p0 + p1 + p2 + p3;
                    int qq = __builtin_amdgcn_cvt_pk_fp8_f32(p0, p1, 0, false);
                    q[t] = __builtin_amdgcn_cvt_pk_fp8_f32(p2, p3, qq, true);
                }
            } else {
#pragma unroll
                for (int t = 0; t < 4; ++t) {
                    float p[4];
#pragma unroll
                    for (int j = 0; j < 4; ++j) {
                        int kk = t * 16 + g * 4 + j;
                        float e = __expf(s[r][t][j]);
                        p[j] = (kk < rem) ? e : 0.f;
                        lsum[r] += p[j];
                    }
                    int qq = __builtin_amdgcn_cvt_pk_fp8_f32(p[0], p[1], 0, false);
                    q[t] = __builtin_amdgcn_cvt_pk_fp8_f32(p[2], p[3], qq, true);
                }
            }
            int x0 = q[0], y0 = q[1];
            asm volatile("v_permlane32_swap_b32 %0, %1" : "+v"(x0), "+v"(y0));
            asm volatile("v_permlane16_swap_b32 %0, %1" : "+v"(x0), "+v"(y0));
            pa[r][0] = (long)(((unsigned long)(unsigned)y0 << 32) | (unsigned)x0);
            int x1 = q[2], y1 = q[3];
            asm volatile("v_permlane32_swap_b32 %0, %1" : "+v"(x1), "+v"(y1));
            asm volatile("v_permlane16_swap_b32 %0, %1" : "+v"(x1), "+v"(y1));
            pa[r][1] = (long)(((unsigned long)(unsigned)y1 << 32) | (unsigned)x1);
        }

        // O += P * V  (V B-frags shared by both rowsets)
#pragma unroll
        for (int sub = 0; sub < 8; ++sub) {
#pragma unroll
            for (int kh = 0; kh < 2; ++kh) {
                long bf = *reinterpret_cast<const long*>(
                    &Vl[cur][(sub * 16 + l16) * 64 + ((((kh * 2) + g1) ^ (l16 & 3)) * 16) + g0 * 8]);
                o[0][sub] = __builtin_amdgcn_mfma_f32_16x16x32_fp8_fp8(pa[0][kh], bf, o[0][sub], 0, 0, 0);
                o[1][sub] = __builtin_amdgcn_mfma_f32_16x16x32_fp8_fp8(pa[1][kh], bf, o[1][sub], 0, 0, 0);
            }
        }

        __builtin_amdgcn_sched_barrier(0);
        __builtin_amdgcn_s_barrier();
        cur ^= 1;
    }

    // row-sums: reduce across g-groups (lane row = l16)
#pragma unroll
    for (int r = 0; r < 2; ++r) {
        float v = lsum[r];
        v += __shfl_xor(v, 16, 64);
        v += __shfl_xor(v, 32, 64);
        if (l < 16) atomicAdd(&Dsum[rowbase + r * 16 + l16], v);
    }
#pragma unroll
    for (int sub = 0; sub < 8; ++sub)
#pragma unroll
        for (int r = 0; r < 2; ++r)
#pragma unroll
            for (int j = 0; j < 4; ++j) {
                int row = rowbase + r * 16 + g * 4 + j;
                atomicAdd(&Onum[(size_t)row * DIM + sub * 16 + l16], o[r][sub][j]);
            }
}

// ---------------------------------------------------------------------------
// Final gather
// ---------------------------------------------------------------------------
__global__ void gather_out(const int* __restrict__ x,
                           const short* __restrict__ langc,
                           const int* __restrict__ slotmap,
                           const float* __restrict__ Onum,
                           const float* __restrict__ Dsum,
                           const float* __restrict__ special,
                           float* __restrict__ out) {
    int i = blockIdx.x;
    int t = threadIdx.x;
    int id = x[i];
    float v;
    if (id < NSPEC) {
        v = special[(size_t)id * DIM + t];
    } else {
        int s = slotmap[id - NSPEC];
        v = bf2f(langc[(size_t)s * DIM + t]) + Onum[(size_t)s * DIM + t] / Dsum[s];
    }
    out[(size_t)i * DIM + t] = v;
}

// ---------------------------------------------------------------------------
extern "C" void kernel_launch(void* const* d_in, const int* in_sizes, int n_in,
                              void* d_out, int out_size, void* d_ws, size_t ws_size,
                              hipStream_t stream) {
    const int*   x        = (const int*)d_in[0];
    const int*   ngram_id = (const int*)d_in[1];
    const int*   seg_id   = (const int*)d_in[2];
    const float* W        = (const float*)d_in[3];   // [32001,128]
    const float* latent   = (const float*)d_in[4];   // [10000,128]
    const float* special  = (const float*)d_in[5];   // [4,128]
    float* out = (float*)d_out;

    // workspace (~10.3 MB); [Onum|Dsum|flags] contiguous -> one memset
    char* ws = (char*)d_ws;
    float* Onum    = (float*)(ws + 0);                       // 4,194,304
    float* Dsum    = (float*)(ws + 4194304);                 //    32,768
    unsigned char* flags = (unsigned char*)(ws + 4227072);   //    32,768
    int*   slotmap = (int*)(ws + 4259840);                   //   128,256
    int*   rowlist = (int*)(ws + 4388096);                   //    32,768
    int*   Uptr    = (int*)(ws + 4420864);                   //       256
    int*   bounds  = (int*)(ws + 4421120);                   //   128,256
    short* langc   = (short*)(ws + 4549376);                 // 2,097,152
    unsigned char* langq = (unsigned char*)(ws + 6646528);   // 1,048,576
    unsigned char* latf8 = (unsigned char*)(ws + 7695104);   // 1,280,000
    unsigned char* latT8 = (unsigned char*)(ws + 8975104);   // 1,294,336 -> 10,269,440

    hipMemsetAsync(ws, 0, 4259840, stream);  // Onum + Dsum + flags

    prep<<<BOUND_BLOCKS + NTOK / 256, 256, 0, stream>>>(x, seg_id, flags, bounds);
    scan_compact<<<1, 1024, 0, stream>>>(flags, slotmap, rowlist, Uptr);
    seg_conv<<<SEG_BLOCKS + CONV_BX * CONV_BY, 256, 0, stream>>>(
        ngram_id, bounds, W, rowlist, Uptr, langc, langq, latent, latf8, latT8);
    flash_latent<<<(MAXU / 128) * KSPLIT, 256, 0, stream>>>(
        langq, latf8, latT8, Uptr, Onum, Dsum);
    gather_out<<<NTOK, 128, 0, stream>>>(x, langc, slotmap, Onum, Dsum, special, out);
}

// Round 5
// 114.215 us; speedup vs baseline: 5.9264x; 1.0603x over previous
//
#include <hip/hip_runtime.h>
#include <hip/hip_bf16.h>

// Problem constants
#define V_WORDS 32000
#define NSPEC 4
#define DIM 128
#define LATENT 10000
#define LT_STRIDE 10112      // padded fp8 V^T row length (bytes)
#define TOTAL_NGRAMS 704000
#define NTOK 8192
#define MAXU 8192
#define KSPLIT 16
#define KCH 640              // k-range per split (last: 10000-15*640=400)
#define BK 64
#define BQBLK 256            // q rows per block (4 waves x 64)
#define SEG_BLOCKS 2048      // MAXU/4
#define BOUND_BLOCKS 2750    // 704000/256
#define CONV_BX 316          // LT_STRIDE/32
#define CONV_BY 4            // 128/32

typedef __attribute__((ext_vector_type(4))) float f32x4;
typedef __attribute__((ext_vector_type(2))) short short2v;

__device__ __forceinline__ short f2bf(float f) {
    __hip_bfloat16 h = __float2bfloat16(f);
    return *reinterpret_cast<short*>(&h);
}
__device__ __forceinline__ float bf2f(short s) {
    unsigned u = ((unsigned)(unsigned short)s) << 16;
    return __uint_as_float(u);
}

// async global->LDS 16B (LDS dest = wave-uniform base + lane*16)
__device__ __forceinline__ void gl_lds16(const void* src, void* dst) {
    __builtin_amdgcn_global_load_lds(
        (const __attribute__((address_space(1))) void*)src,
        (__attribute__((address_space(3))) void*)dst, 16, 0, 0);
}

// ---------------------------------------------------------------------------
// prep: seg bounds (blocks 0..2749) + atomic compaction (blocks 2750..)
// ---------------------------------------------------------------------------
__global__ void prep(const int* __restrict__ x, const int* __restrict__ seg_ids,
                     int* __restrict__ flags, int* __restrict__ slotmap,
                     int* __restrict__ rowlist, int* __restrict__ U,
                     int* __restrict__ bounds) {
    int b = blockIdx.x;
    int t = threadIdx.x;
    if (b < BOUND_BLOCKS) {
        int i = b * 256 + t;
        int cur = seg_ids[i];
        int prev = (i == 0) ? -1 : seg_ids[i - 1];
        for (int v = prev + 1; v <= cur; ++v) bounds[v] = i;
        if (i == TOTAL_NGRAMS - 1)
            for (int v = cur + 1; v <= V_WORDS; ++v) bounds[v] = TOTAL_NGRAMS;
    } else {
        int i = (b - BOUND_BLOCKS) * 256 + t;
        if (i < NTOK) {
            int id = x[i];
            if (id >= NSPEC) {
                int v = id - NSPEC;
                if (atomicExch(&flags[v], 1) == 0) {
                    int s = atomicAdd(U, 1);
                    rowlist[s] = v;
                    slotmap[v] = s;
                }
            }
        }
    }
}

// ---------------------------------------------------------------------------
// seg_conv: blocks 0..2047 = EmbeddingBag+tanh (bf16 + fp8 out);
//           blocks 2048..  = latent fp8 convert + fp8 transpose
// ---------------------------------------------------------------------------
__global__ __launch_bounds__(256)
void seg_conv(const int* __restrict__ ngram_ids, const int* __restrict__ bounds,
              const float* __restrict__ W, const int* __restrict__ rowlist,
              const int* __restrict__ Uptr, short* __restrict__ langc,
              unsigned char* __restrict__ langq,
              const float* __restrict__ latent,
              unsigned char* __restrict__ latf8, unsigned char* __restrict__ latT8) {
    __shared__ float tile[32][36];
    int t = threadIdx.x;
    if (blockIdx.x < SEG_BLOCKS) {
        int slot = blockIdx.x * 4 + (t >> 6);
        if (slot >= *Uptr) return;
        int v = rowlist[slot];
        int l = t & 63;
        int start = bounds[v], end = bounds[v + 1];
        float ax = 0.f, ay = 0.f;
        for (int j = start; j < end; ++j) {
            int id = ngram_ids[j];
            float2 row = *reinterpret_cast<const float2*>(W + (size_t)id * DIM + l * 2);
            ax += row.x; ay += row.y;
        }
        float tx = tanhf(ax), ty = tanhf(ay);
        short2v o; o.x = f2bf(tx); o.y = f2bf(ty);
        *reinterpret_cast<short2v*>(langc + (size_t)slot * DIM + l * 2) = o;
        int pk = __builtin_amdgcn_cvt_pk_fp8_f32(tx, ty, 0, false);
        *reinterpret_cast<unsigned short*>(langq + (size_t)slot * DIM + l * 2) =
            (unsigned short)(pk & 0xFFFF);
    } else {
        int bx = blockIdx.x - SEG_BLOCKS;
        int n0 = (bx % CONV_BX) * 32;
        int d0 = (bx / CONV_BX) * 32;
        int nl = t >> 3, dq = t & 7;
        int n = n0 + nl, d = d0 + dq * 4;
        float4 v = {0.f, 0.f, 0.f, 0.f};
        if (n < LATENT) v = *reinterpret_cast<const float4*>(latent + (size_t)n * DIM + d);
        *reinterpret_cast<float4*>(&tile[nl][dq * 4]) = v;
        if (n < LATENT) {
            int pk = __builtin_amdgcn_cvt_pk_fp8_f32(v.x, v.y, 0, false);
            pk = __builtin_amdgcn_cvt_pk_fp8_f32(v.z, v.w, pk, true);
            *reinterpret_cast<unsigned*>(latf8 + (size_t)n * DIM + d) = (unsigned)pk;
        }
        __syncthreads();
#pragma unroll
        for (int u = 0; u < 2; ++u) {
            int it = t + u * 256;
            int dl = it >> 4, np = it & 15;
            float v0 = tile[np * 2][dl], v1 = tile[np * 2 + 1][dl];
            int pk = __builtin_amdgcn_cvt_pk_fp8_f32(v0, v1, 0, false);
            *reinterpret_cast<unsigned short*>(
                latT8 + (size_t)(d0 + dl) * LT_STRIDE + n0 + np * 2) =
                (unsigned short)(pk & 0xFFFF);
        }
    }
}

// ---------------------------------------------------------------------------
// Flash (fp8, 64 q/wave): Onum += sum_k exp(S)V ; Dsum += sum_k exp(S)
// Swapped QK^T (mfma(K,Q) -> S^T): P lane-local; packed to fp8 via cvt_pk +
// permlane{32,16}_swap. K/V B-frags shared across 4 q-tiles per wave -> LDS
// bytes/FLOP halved vs 32q. 512 blocks (2/CU), double-buffer, counted vmcnt.
// ---------------------------------------------------------------------------
__global__ __launch_bounds__(256, 2)
void flash_latent(const unsigned char* __restrict__ langq,  // fp8 [MAXU][128]
                  const unsigned char* __restrict__ latf8,  // fp8 [LATENT][128]
                  const unsigned char* __restrict__ latT8,  // fp8 [128][LT_STRIDE]
                  const int* __restrict__ Uptr,
                  float* __restrict__ Onum,    // [MAXU][128] f32 (zeroed)
                  float* __restrict__ Dsum) {  // [MAXU] f32 (zeroed)
    const int U = *Uptr;
    const int chunk = blockIdx.x >> 4;   // 0..31
    const int ks = blockIdx.x & 15;      // K-split
    if (chunk * BQBLK >= U) return;

    __shared__ __align__(16) unsigned char Kl[2][BK * DIM];   // 2 x 8KB
    __shared__ __align__(16) unsigned char Vl[2][DIM * BK];   // 2 x 8KB

    const int tid = threadIdx.x;
    const int w = tid >> 6, l = tid & 63, l16 = l & 15, g = l >> 4;
    const int g1 = g >> 1, g0 = g & 1;
    const int rowbase = chunk * BQBLK + w * 64;

    // Q fp8 frags: lane holds Q[qt, row l16][c*32 + g*8 + 0..7]
    long qf[4][4];
#pragma unroll
    for (int qt = 0; qt < 4; ++qt)
#pragma unroll
        for (int c = 0; c < 4; ++c)
            qf[qt][c] = *reinterpret_cast<const long*>(
                langq + (size_t)(rowbase + qt * 16 + l16) * DIM + c * 32 + g * 8);

    f32x4 o[4][8];
#pragma unroll
    for (int qt = 0; qt < 4; ++qt)
#pragma unroll
        for (int s = 0; s < 8; ++s) o[qt][s] = (f32x4){0.f, 0.f, 0.f, 0.f};
    float lsum[4] = {0.f, 0.f, 0.f, 0.f};

    const int kstart = ks * KCH;
    const int kend = (kstart + KCH < LATENT) ? (kstart + KCH) : LATENT;
    const int niter = (kend - kstart + BK - 1) / BK;

#define STAGE(KT, BUF)                                                              \
    do {                                                                            \
        const int k0s = kstart + (KT) * BK;                                         \
        _Pragma("unroll")                                                           \
        for (int i = 0; i < 2; ++i) {                                               \
            int c = (w * 2 + i) * 64 + l;                                           \
            int rr = c >> 3, s16 = c & 7;                                           \
            int gk = k0s + rr; if (gk > LATENT - 1) gk = LATENT - 1;                \
            gl_lds16(latf8 + (size_t)gk * DIM + ((s16 ^ (rr & 7)) * 16),            \
                     &Kl[BUF][(w * 2 + i) * 1024]);                                 \
        }                                                                           \
        _Pragma("unroll")                                                           \
        for (int i = 0; i < 2; ++i) {                                               \
            int c = (w * 2 + i) * 64 + l;                                           \
            int dd = c >> 2, s16 = c & 3;                                           \
            gl_lds16(latT8 + (size_t)dd * LT_STRIDE + k0s + ((s16 ^ (dd & 3)) * 16),\
                     &Vl[BUF][(w * 2 + i) * 1024]);                                 \
        }                                                                           \
    } while (0)

    STAGE(0, 0);
    int cur = 0;

    for (int kt = 0; kt < niter; ++kt) {
        if (kt + 1 < niter) {
            STAGE(kt + 1, cur ^ 1);
            asm volatile("s_waitcnt vmcnt(4)" ::: "memory");
        } else {
            asm volatile("s_waitcnt vmcnt(0)" ::: "memory");
        }
        __builtin_amdgcn_s_barrier();
        __builtin_amdgcn_sched_barrier(0);

        const int k0 = kstart + kt * BK;
        const int rem = kend - k0;

        // QK + exp + pack, per 16-k subtile (keeps s[] transient: 16 VGPR)
        int pw[4][4];   // packed exp(S) fp8 words [qt][t4]
#pragma unroll
        for (int t4 = 0; t4 < 4; ++t4) {
            f32x4 s[4];
#pragma unroll
            for (int qt = 0; qt < 4; ++qt) s[qt] = (f32x4){0.f, 0.f, 0.f, 0.f};
#pragma unroll
            for (int c = 0; c < 4; ++c) {
                long af = *reinterpret_cast<const long*>(
                    &Kl[cur][(t4 * 16 + l16) * 128 + (((c * 2 + g1) ^ (l16 & 7)) * 16) + g0 * 8]);
#pragma unroll
                for (int qt = 0; qt < 4; ++qt)
                    s[qt] = __builtin_amdgcn_mfma_f32_16x16x32_fp8_fp8(af, qf[qt][c], s[qt], 0, 0, 0);
            }
            if (rem >= BK) {
#pragma unroll
                for (int qt = 0; qt < 4; ++qt) {
                    float p0 = __expf(s[qt][0]), p1 = __expf(s[qt][1]);
                    float p2 = __expf(s[qt][2]), p3 = __expf(s[qt][3]);
                    lsum[qt] += p0 + p1 + p2 + p3;
                    int qq = __builtin_amdgcn_cvt_pk_fp8_f32(p0, p1, 0, false);
                    pw[qt][t4] = __builtin_amdgcn_cvt_pk_fp8_f32(p2, p3, qq, true);
                }
            } else {
#pragma unroll
                for (int qt = 0; qt < 4; ++qt) {
                    float p[4];
#pragma unroll
                    for (int j = 0; j < 4; ++j) {
                        int kk = t4 * 16 + g * 4 + j;
                        float e = __expf(s[qt][j]);
                        p[j] = (kk < rem) ? e : 0.f;
                        lsum[qt] += p[j];
                    }
                    int qq = __builtin_amdgcn_cvt_pk_fp8_f32(p[0], p[1], 0, false);
                    pw[qt][t4] = __builtin_amdgcn_cvt_pk_fp8_f32(p[2], p[3], qq, true);
                }
            }
        }

        // permlane assembly of PV A-frags
        long pa[4][2];
#pragma unroll
        for (int qt = 0; qt < 4; ++qt) {
            int x0 = pw[qt][0], y0 = pw[qt][1];
            asm volatile("v_permlane32_swap_b32 %0, %1" : "+v"(x0), "+v"(y0));
            asm volatile("v_permlane16_swap_b32 %0, %1" : "+v"(x0), "+v"(y0));
            pa[qt][0] = (long)(((unsigned long)(unsigned)y0 << 32) | (unsigned)x0);
            int x1 = pw[qt][2], y1 = pw[qt][3];
            asm volatile("v_permlane32_swap_b32 %0, %1" : "+v"(x1), "+v"(y1));
            asm volatile("v_permlane16_swap_b32 %0, %1" : "+v"(x1), "+v"(y1));
            pa[qt][1] = (long)(((unsigned long)(unsigned)y1 << 32) | (unsigned)x1);
        }

        // O += P * V  (V B-frags shared across 4 q-tiles)
#pragma unroll
        for (int sub = 0; sub < 8; ++sub) {
#pragma unroll
            for (int kh = 0; kh < 2; ++kh) {
                long bf = *reinterpret_cast<const long*>(
                    &Vl[cur][(sub * 16 + l16) * 64 + ((((kh * 2) + g1) ^ (l16 & 3)) * 16) + g0 * 8]);
#pragma unroll
                for (int qt = 0; qt < 4; ++qt)
                    o[qt][sub] = __builtin_amdgcn_mfma_f32_16x16x32_fp8_fp8(pa[qt][kh], bf, o[qt][sub], 0, 0, 0);
            }
        }

        __builtin_amdgcn_sched_barrier(0);
        __builtin_amdgcn_s_barrier();
        cur ^= 1;
    }

    // row-sums reduce across g-groups (lane q-col = l16 per qt)
#pragma unroll
    for (int qt = 0; qt < 4; ++qt) {
        float v = lsum[qt];
        v += __shfl_xor(v, 16, 64);
        v += __shfl_xor(v, 32, 64);
        if (l < 16) atomicAdd(&Dsum[rowbase + qt * 16 + l16], v);
    }
#pragma unroll
    for (int sub = 0; sub < 8; ++sub)
#pragma unroll
        for (int qt = 0; qt < 4; ++qt)
#pragma unroll
            for (int j = 0; j < 4; ++j) {
                int row = rowbase + qt * 16 + g * 4 + j;
                atomicAdd(&Onum[(size_t)row * DIM + sub * 16 + l16], o[qt][sub][j]);
            }
}

// ---------------------------------------------------------------------------
// Final gather: 2 tokens per 256-thr block
// ---------------------------------------------------------------------------
__global__ void gather_out(const int* __restrict__ x,
                           const short* __restrict__ langc,
                           const int* __restrict__ slotmap,
                           const float* __restrict__ Onum,
                           const float* __restrict__ Dsum,
                           const float* __restrict__ special,
                           float* __restrict__ out) {
    int i = blockIdx.x * 2 + (threadIdx.x >> 7);
    int t = threadIdx.x & 127;
    int id = x[i];
    float v;
    if (id < NSPEC) {
        v = special[(size_t)id * DIM + t];
    } else {
        int s = slotmap[id - NSPEC];
        v = bf2f(langc[(size_t)s * DIM + t]) + Onum[(size_t)s * DIM + t] / Dsum[s];
    }
    out[(size_t)i * DIM + t] = v;
}

// ---------------------------------------------------------------------------
extern "C" void kernel_launch(void* const* d_in, const int* in_sizes, int n_in,
                              void* d_out, int out_size, void* d_ws, size_t ws_size,
                              hipStream_t stream) {
    const int*   x        = (const int*)d_in[0];
    const int*   ngram_id = (const int*)d_in[1];
    const int*   seg_id   = (const int*)d_in[2];
    const float* W        = (const float*)d_in[3];   // [32001,128]
    const float* latent   = (const float*)d_in[4];   // [10000,128]
    const float* special  = (const float*)d_in[5];   // [4,128]
    float* out = (float*)d_out;

    // workspace (~10.4 MB); [Onum|Dsum|flags|Uptr] contiguous -> one memset
    char* ws = (char*)d_ws;
    float* Onum    = (float*)(ws + 0);                       // 4,194,304
    float* Dsum    = (float*)(ws + 4194304);                 //    32,768
    int*   flags   = (int*)(ws + 4227072);                   //   131,072 (32000 used)
    int*   Uptr    = (int*)(ws + 4358144);                   //       256
    int*   slotmap = (int*)(ws + 4358400);                   //   128,256
    int*   rowlist = (int*)(ws + 4486656);                   //    32,768
    int*   bounds  = (int*)(ws + 4519424);                   //   128,256
    short* langc   = (short*)(ws + 4647680);                 // 2,097,152
    unsigned char* langq = (unsigned char*)(ws + 6744832);   // 1,048,576
    unsigned char* latf8 = (unsigned char*)(ws + 7793408);   // 1,280,000
    unsigned char* latT8 = (unsigned char*)(ws + 9073408);   // 1,294,336 -> 10,367,744

    hipMemsetAsync(ws, 0, 4358400, stream);  // Onum + Dsum + flags + Uptr

    prep<<<BOUND_BLOCKS + NTOK / 256, 256, 0, stream>>>(
        x, seg_id, flags, slotmap, rowlist, Uptr, bounds);
    seg_conv<<<SEG_BLOCKS + CONV_BX * CONV_BY, 256, 0, stream>>>(
        ngram_id, bounds, W, rowlist, Uptr, langc, langq, latent, latf8, latT8);
    flash_latent<<<(MAXU / BQBLK) * KSPLIT, 256, 0, stream>>>(
        langq, latf8, latT8, Uptr, Onum, Dsum);
    gather_out<<<NTOK / 2, 256, 0, stream>>>(x, langc, slotmap, Onum, Dsum, special, out);
}